// Round 15
// baseline (43.572 us; speedup 1.0000x reference)
//
#include <hip/hip_runtime.h>

typedef float v2f __attribute__((ext_vector_type(2)));
typedef _Float16 h8 __attribute__((ext_vector_type(8)));

constexpr int B = 4, H = 8, N = 256, D = 64;
constexpr int QBLK = 16;
constexpr int PATTN_OFF = B * H * N * D;   // 524288
constexpr int NROWS = B * H * N;           // 8192

// ws layout: qp[NROWS*64] f32 | kpbh[NROWS*64] f16 | cq6[NROWS] | ck6[NROWS] | w4[64]

// proj: unchanged from R14.
__global__ __launch_bounds__(256, 2) void proj_kernel(
    const float* __restrict__ q, const float* __restrict__ k,
    const float* __restrict__ W_h, const float* __restrict__ b_h,
    const float* __restrict__ W_o, const float* __restrict__ b_o,
    float* __restrict__ qp, _Float16* __restrict__ kpbh,
    float* __restrict__ cq6, float* __restrict__ ck6, float* __restrict__ w4)
{
    __shared__ float WT[128 * 65];
    int t = threadIdx.x;
    int lane = t & 63;
    int wid = __builtin_amdgcn_readfirstlane(t >> 6);
    int bid = blockIdx.x;
    int work = (bid & 7) * 64 + (bid >> 3);   // 512 = 8*64 bijective XCD swizzle

    #pragma unroll
    for (int i = 0; i < 8; ++i) {
        int fidx = (t + i * 256) * 4;
        float4 w = *reinterpret_cast<const float4*>(W_h + fidx);
        int e = fidx >> 7, d = fidx & 127;
        WT[(d + 0) * 65 + e] = w.x;
        WT[(d + 1) * 65 + e] = w.y;
        WT[(d + 2) * 65 + e] = w.z;
        WT[(d + 3) * 65 + e] = w.w;
    }
    if (bid == 0 && t < 64) w4[t] = 0.4f * W_o[t];
    __syncthreads();

    int rbase = work * 16 + wid * 4;   // 4 rows per wave, e = lane
    float accq[4] = {}, acck[4] = {};
    #pragma unroll
    for (int d0 = 0; d0 < 64; d0 += 16) {
        float wq[16], wk[16];
        #pragma unroll
        for (int d = 0; d < 16; ++d) {
            wq[d] = WT[(d0 + d) * 65 + lane];
            wk[d] = WT[(64 + d0 + d) * 65 + lane];
        }
        #pragma unroll
        for (int j = 0; j < 4; ++j) {
            const float* qrow = q + (rbase + j) * 64 + d0;   // wave-uniform -> s_load
            const float* krow = k + (rbase + j) * 64 + d0;
            #pragma unroll
            for (int d = 0; d < 16; ++d) {
                accq[j] = fmaf(qrow[d], wq[d], accq[j]);
                acck[j] = fmaf(krow[d], wk[d], acck[j]);
            }
        }
    }
    float bh_e = b_h[lane];
    float wo = W_o[lane];
    float bo = b_o[0];
    #pragma unroll
    for (int j = 0; j < 4; ++j) {
        float aq = accq[j];
        float ak = acck[j] + bh_e;
        qp[(rbase + j) * 64 + lane] = aq;
        kpbh[(rbase + j) * 64 + lane] = (_Float16)ak;
        float sq = wo * aq, sk = wo * ak;
        #pragma unroll
        for (int off = 32; off > 0; off >>= 1) {
            sq += __shfl_xor(sq, off, 64);
            sk += __shfl_xor(sk, off, 64);
        }
        if (lane == 0) {
            cq6[rbase + j] = 0.6f * sq + bo;
            ck6[rbase + j] = 0.6f * sk;
        }
    }
}

// attn: QBLK=16, grid 512 (2 blocks/CU exact fill), 512 thr. e-split halves,
// packed-fp32 scores, f16 kv, no-max softmax. Phase B+C merged: wave wid owns
// rows {wid, wid+8} -> in-wave shfl row-sum, no red_s, 3 barriers total.
__global__ __launch_bounds__(512, 2) void attn_kernel(
    const float* __restrict__ qp, const _Float16* __restrict__ kpbh,
    const float* __restrict__ V, const int* __restrict__ mask,
    const float* __restrict__ cq6, const float* __restrict__ ck6,
    const float* __restrict__ w4g,
    float* __restrict__ out)
{
    __shared__ float sc[8192];        // scores [half][row][m] (32 KB); later pv partials [chunk][row][d]
    __shared__ _Float16 pf[4096];     // [row][m] p as f16 (8 KB)

    int t = threadIdx.x;
    int lane = t & 63;
    int wid = __builtin_amdgcn_readfirstlane(t >> 6);   // 0..7
    int h = wid >> 2;                // 0/1, wave-uniform
    int m = t & 255;
    int bid = blockIdx.x;
    int work = (bid & 7) * 64 + (bid >> 3);   // 512 = 8*64 bijective
    int bh = work >> 4;              // 16 tiles per bh
    int nb = work & 15;
    int b = bh >> 3;
    int n0 = nb * QBLK;
    int kvbase = bh * N * 64;

    // kv: kpbh[m][32h .. 32h+31] as 4 x h8 (64 B contiguous, coalesced)
    const h8* kph = reinterpret_cast<const h8*>(kpbh + kvbase + m * 64 + h * 32);
    h8 kh0 = kph[0], kh1 = kph[1], kh2 = kph[2], kh3 = kph[3];

    // mask prefetch for phase BC: rows wid, wid+8; 4 m-chunks each (0/1 floats)
    float mfv[2][4];
    #pragma unroll
    for (int j = 0; j < 2; ++j) {
        int row = n0 + wid + j * 8;
        #pragma unroll
        for (int c = 0; c < 4; ++c)
            mfv[j][c] = (mask[(b * N + row) * N + c * 64 + lane] != 0) ? 1.0f : 0.0f;
    }

    float ckt = (h == 0) ? ck6[bh * N + m] : 0.f;

    // ---- phase A: packed partial scores for 16 rows over this half's 32 e's ----
    v2f sp2[QBLK];
    const float* cq = cq6 + bh * N + n0;   // uniform
    #pragma unroll
    for (int r = 0; r < QBLK; ++r) {
        float init = (h == 0) ? (cq[r] + ckt) : 0.f;
        sp2[r] = (v2f){init, 0.f};
    }

    const v2f* qr2 = reinterpret_cast<const v2f*>(qp + (bh * N + n0) * 64 + h * 32);  // uniform
    const v2f* w42 = reinterpret_cast<const v2f*>(w4g + h * 32);                      // uniform
    #pragma unroll
    for (int chunk = 0; chunk < 4; ++chunk) {
        h8 kc = (chunk == 0) ? kh0 : (chunk == 1) ? kh1 : (chunk == 2) ? kh2 : kh3;
        #pragma unroll
        for (int p = 0; p < 4; ++p) {
            v2f w2 = w42[chunk * 4 + p];
            v2f k2 = (v2f){(float)kc[2 * p], (float)kc[2 * p + 1]};
            #pragma unroll
            for (int r = 0; r < QBLK; ++r) {
                v2f x = qr2[r * 32 + chunk * 4 + p] + k2;           // v_pk_add_f32
                v2f ax = __builtin_elementwise_max(x, -x);          // v_pk_max_f32
                sp2[r] = __builtin_elementwise_fma(w2, ax, sp2[r]); // v_pk_fma_f32
            }
        }
    }
    #pragma unroll
    for (int r = 0; r < QBLK; ++r)
        sc[h * 4096 + r * 256 + m] = sp2[r].x + sp2[r].y;   // conflict-free

    // V prefetch for phase D group 0 (8 values)
    const float* Vp = V + kvbase + wid * 32 * 64 + lane;
    float vpre[8];
    #pragma unroll
    for (int g = 0; g < 8; ++g) vpre[g] = Vp[g * 64];
    __syncthreads();   // --- barrier 1 ---

    // ---- phase BC: wave wid owns rows wid, wid+8; full in-wave softmax ----
    #pragma unroll
    for (int j = 0; j < 2; ++j) {
        int r = wid + j * 8;
        float pv4[4];
        float l = 0.f;
        #pragma unroll
        for (int c = 0; c < 4; ++c) {
            int mm = c * 64 + lane;
            float s = sc[r * 256 + mm] + sc[4096 + r * 256 + mm];
            float p = __expf(s) * mfv[j][c];
            pv4[c] = p;
            l += p;
        }
        #pragma unroll
        for (int off = 32; off > 0; off >>= 1) l += __shfl_xor(l, off, 64);
        float gs = __frcp_rn(l);
        #pragma unroll
        for (int c = 0; c < 4; ++c) {
            int mm = c * 64 + lane;
            float pn = pv4[c] * gs;
            pf[r * 256 + mm] = (_Float16)pn;                      // ds_write_b16
            out[PATTN_OFF + (bh * N + n0 + r) * N + mm] = pn;     // coalesced fp32
        }
    }
    __syncthreads();   // --- barrier 2 (pf ready; sc scores dead after this) ---

    // ---- phase D: PV. wid = m-chunk of 32, lane = d; f16 p broadcasts ----
    float acc[QBLK] = {};
    {   // group 0 from prefetch
        #pragma unroll
        for (int r = 0; r < QBLK; ++r) {
            h8 ph = *reinterpret_cast<const h8*>(&pf[r * 256 + wid * 32]);
            #pragma unroll
            for (int g = 0; g < 8; ++g)
                acc[r] = fmaf((float)ph[g], vpre[g], acc[r]);   // -> v_fma_mix_f32
        }
    }
    #pragma unroll
    for (int j = 8; j < 32; j += 8) {
        float vv[8];
        #pragma unroll
        for (int g = 0; g < 8; ++g) vv[g] = Vp[(j + g) * 64];
        #pragma unroll
        for (int r = 0; r < QBLK; ++r) {
            h8 ph = *reinterpret_cast<const h8*>(&pf[r * 256 + wid * 32 + j]);
            #pragma unroll
            for (int g = 0; g < 8; ++g)
                acc[r] = fmaf((float)ph[g], vv[g], acc[r]);
        }
    }
    // sc scores dead since barrier 2; write PV partials (pf untouched -> no race)
    #pragma unroll
    for (int r = 0; r < QBLK; ++r)
        sc[wid * 1024 + r * 64 + lane] = acc[r];
    __syncthreads();   // --- barrier 3 ---

    // final: thread t handles rows (t>>6) and (t>>6)+8, d = lane
    #pragma unroll
    for (int j = 0; j < 2; ++j) {
        int rr = (t >> 6) + j * 8;
        float o = 0.f;
        #pragma unroll
        for (int mc = 0; mc < 8; ++mc)
            o += sc[mc * 1024 + rr * 64 + lane];
        out[(bh * N + n0 + rr) * 64 + lane] = o;
    }
}

extern "C" void kernel_launch(void* const* d_in, const int* in_sizes, int n_in,
                              void* d_out, int out_size, void* d_ws, size_t ws_size,
                              hipStream_t stream) {
    const float* q    = (const float*)d_in[0];
    const float* k    = (const float*)d_in[1];
    const float* v    = (const float*)d_in[2];
    const int*   mask = (const int*)d_in[3];
    const float* W_h  = (const float*)d_in[4];
    const float* b_h  = (const float*)d_in[5];
    const float* W_o  = (const float*)d_in[6];
    const float* b_o  = (const float*)d_in[7];
    float* out = (float*)d_out;

    float* qp       = (float*)d_ws;
    _Float16* kpbh  = (_Float16*)(qp + NROWS * 64);
    float* cq6      = (float*)(qp + NROWS * 64 + NROWS * 64);
    float* ck6      = cq6 + NROWS;
    float* w4       = ck6 + NROWS;

    proj_kernel<<<NROWS / 16, 256, 0, stream>>>(q, k, W_h, b_h, W_o, b_o, qp, kpbh, cq6, ck6, w4);
    attn_kernel<<<B * H * (N / QBLK), 512, 0, stream>>>(qp, kpbh, v, mask, cq6, ck6, w4, out);
}

// Round 16
// 42.173 us; speedup vs baseline: 1.0332x; 1.0332x over previous
//
#include <hip/hip_runtime.h>

typedef float v2f __attribute__((ext_vector_type(2)));
typedef _Float16 h8 __attribute__((ext_vector_type(8)));

constexpr int B = 4, H = 8, N = 256, D = 64;
constexpr int QBLK = 8;
constexpr int PATTN_OFF = B * H * N * D;   // 524288
constexpr int NROWS = B * H * N;           // 8192

// ws layout: qp[NROWS*64] f32 | kpbh[NROWS*64] f16 | cq6[NROWS] | ck6[NROWS] | w4[64]

// proj: unchanged from R14.
__global__ __launch_bounds__(256, 2) void proj_kernel(
    const float* __restrict__ q, const float* __restrict__ k,
    const float* __restrict__ W_h, const float* __restrict__ b_h,
    const float* __restrict__ W_o, const float* __restrict__ b_o,
    float* __restrict__ qp, _Float16* __restrict__ kpbh,
    float* __restrict__ cq6, float* __restrict__ ck6, float* __restrict__ w4)
{
    __shared__ float WT[128 * 65];
    int t = threadIdx.x;
    int lane = t & 63;
    int wid = __builtin_amdgcn_readfirstlane(t >> 6);
    int bid = blockIdx.x;
    int work = (bid & 7) * 64 + (bid >> 3);   // 512 = 8*64 bijective XCD swizzle

    #pragma unroll
    for (int i = 0; i < 8; ++i) {
        int fidx = (t + i * 256) * 4;
        float4 w = *reinterpret_cast<const float4*>(W_h + fidx);
        int e = fidx >> 7, d = fidx & 127;
        WT[(d + 0) * 65 + e] = w.x;
        WT[(d + 1) * 65 + e] = w.y;
        WT[(d + 2) * 65 + e] = w.z;
        WT[(d + 3) * 65 + e] = w.w;
    }
    if (bid == 0 && t < 64) w4[t] = 0.4f * W_o[t];
    __syncthreads();

    int rbase = work * 16 + wid * 4;   // 4 rows per wave, e = lane
    float accq[4] = {}, acck[4] = {};
    #pragma unroll
    for (int d0 = 0; d0 < 64; d0 += 16) {
        float wq[16], wk[16];
        #pragma unroll
        for (int d = 0; d < 16; ++d) {
            wq[d] = WT[(d0 + d) * 65 + lane];
            wk[d] = WT[(64 + d0 + d) * 65 + lane];
        }
        #pragma unroll
        for (int j = 0; j < 4; ++j) {
            const float* qrow = q + (rbase + j) * 64 + d0;   // wave-uniform -> s_load
            const float* krow = k + (rbase + j) * 64 + d0;
            #pragma unroll
            for (int d = 0; d < 16; ++d) {
                accq[j] = fmaf(qrow[d], wq[d], accq[j]);
                acck[j] = fmaf(krow[d], wk[d], acck[j]);
            }
        }
    }
    float bh_e = b_h[lane];
    float wo = W_o[lane];
    float bo = b_o[0];
    #pragma unroll
    for (int j = 0; j < 4; ++j) {
        float aq = accq[j];
        float ak = acck[j] + bh_e;
        qp[(rbase + j) * 64 + lane] = aq;
        kpbh[(rbase + j) * 64 + lane] = (_Float16)ak;
        float sq = wo * aq, sk = wo * ak;
        #pragma unroll
        for (int off = 32; off > 0; off >>= 1) {
            sq += __shfl_xor(sq, off, 64);
            sk += __shfl_xor(sk, off, 64);
        }
        if (lane == 0) {
            cq6[rbase + j] = 0.6f * sq + bo;
            ck6[rbase + j] = 0.6f * sk;
        }
    }
}

// attn: 256 threads, QBLK=8, grid 1024. NO e-split: thread m computes the full
// 64-e score for 8 rows (scores never touch LDS). f16 kv (128 B/thread),
// packed-fp32 A, no-max softmax, f16 p broadcasts in D. 3 barriers.
__global__ __launch_bounds__(256, 4) void attn_kernel(
    const float* __restrict__ qp, const _Float16* __restrict__ kpbh,
    const float* __restrict__ V, const int* __restrict__ mask,
    const float* __restrict__ cq6, const float* __restrict__ ck6,
    const float* __restrict__ w4g,
    float* __restrict__ out)
{
    __shared__ _Float16 pf[2048];     // [row][m] p as f16 (4 KB)
    __shared__ float pv[2048];        // [chunk][row][d] PV partials (8 KB)
    __shared__ float red_s[4][QBLK];

    int t = threadIdx.x;
    int lane = t & 63;
    int wid = __builtin_amdgcn_readfirstlane(t >> 6);   // 0..3
    int m = t;                        // column owned by this thread
    int bid = blockIdx.x;
    int work = (bid & 7) * 128 + (bid >> 3);   // 1024 = 8*128 bijective
    int bh = work >> 5;
    int nb = work & 31;
    int b = bh >> 3;
    int n0 = nb * QBLK;
    int kvbase = bh * N * 64;

    // kv: full row m as f16, 128 B contiguous (8 x h8 dwordx4 loads)
    const h8* kph = reinterpret_cast<const h8*>(kpbh + kvbase + m * 64);
    h8 kh[8];
    #pragma unroll
    for (int c = 0; c < 8; ++c) kh[c] = kph[c];

    // mask for all 8 rows at column m (coalesced)
    float mf[QBLK];
    #pragma unroll
    for (int r = 0; r < QBLK; ++r)
        mf[r] = (mask[(b * N + n0 + r) * N + m] != 0) ? 1.0f : 0.0f;

    float ckt = ck6[bh * N + m];

    // ---- phase A: full scores for 8 rows, packed fp32, all in registers ----
    v2f sp2[QBLK];
    const float* cq = cq6 + bh * N + n0;   // uniform
    #pragma unroll
    for (int r = 0; r < QBLK; ++r) sp2[r] = (v2f){cq[r] + ckt, 0.f};

    const v2f* qr2 = reinterpret_cast<const v2f*>(qp + (bh * N + n0) * 64);  // uniform
    const v2f* w42 = reinterpret_cast<const v2f*>(w4g);                      // uniform
    #pragma unroll
    for (int c = 0; c < 8; ++c) {
        h8 kc = kh[c];
        #pragma unroll
        for (int p = 0; p < 4; ++p) {
            v2f w2 = w42[c * 4 + p];
            v2f k2 = (v2f){(float)kc[2 * p], (float)kc[2 * p + 1]};
            #pragma unroll
            for (int r = 0; r < QBLK; ++r) {
                v2f x = qr2[r * 32 + c * 4 + p] + k2;               // v_pk_add_f32
                v2f ax = __builtin_elementwise_max(x, -x);          // v_pk_max_f32
                sp2[r] = __builtin_elementwise_fma(w2, ax, sp2[r]); // v_pk_fma_f32
            }
        }
    }

    // V prefetch for phase D group 0: wave wid owns m-chunk [wid*64, wid*64+64)
    const float* Vp = V + kvbase + (wid * 64) * 64 + lane;
    float vpre[8];
    #pragma unroll
    for (int g = 0; g < 8; ++g) vpre[g] = Vp[g * 64];

    // ---- phase B: exp + per-wave row sums (scores stay in registers) ----
    float p8[QBLK];
    #pragma unroll
    for (int r = 0; r < QBLK; ++r) {
        float s = sp2[r].x + sp2[r].y;
        float p = __expf(s) * mf[r];
        p8[r] = p;
        float l = p;
        #pragma unroll
        for (int off = 32; off > 0; off >>= 1) l += __shfl_xor(l, off, 64);
        if (lane == 0) red_s[wid][r] = l;
    }
    __syncthreads();   // --- barrier 1 ---

    // ---- phase C: merge 4 wave-sums per row; write p_attn + pf ----
    #pragma unroll
    for (int r = 0; r < QBLK; ++r) {
        float gs = red_s[0][r] + red_s[1][r] + red_s[2][r] + red_s[3][r];
        float pn = p8[r] * __frcp_rn(gs);
        pf[r * 256 + m] = (_Float16)pn;                      // ds_write_b16
        out[PATTN_OFF + (bh * N + n0 + r) * N + m] = pn;     // coalesced fp32
    }
    __syncthreads();   // --- barrier 2 ---

    // ---- phase D: PV. wave wid = m-chunk of 64, lane = d; f16 p broadcasts ----
    float acc[QBLK] = {};
    {   // group 0 from prefetch
        #pragma unroll
        for (int r = 0; r < QBLK; ++r) {
            h8 ph = *reinterpret_cast<const h8*>(&pf[r * 256 + wid * 64]);
            #pragma unroll
            for (int g = 0; g < 8; ++g)
                acc[r] = fmaf((float)ph[g], vpre[g], acc[r]);   // -> v_fma_mix_f32
        }
    }
    #pragma unroll
    for (int j = 8; j < 64; j += 8) {
        float vv[8];
        #pragma unroll
        for (int g = 0; g < 8; ++g) vv[g] = Vp[(j + g) * 64];
        #pragma unroll
        for (int r = 0; r < QBLK; ++r) {
            h8 ph = *reinterpret_cast<const h8*>(&pf[r * 256 + wid * 64 + j]);
            #pragma unroll
            for (int g = 0; g < 8; ++g)
                acc[r] = fmaf((float)ph[g], vv[g], acc[r]);
        }
    }
    #pragma unroll
    for (int r = 0; r < QBLK; ++r)
        pv[wid * 512 + r * 64 + lane] = acc[r];
    __syncthreads();   // --- barrier 3 ---

    // final: thread t handles rows (t>>6) and (t>>6)+4, d = lane
    #pragma unroll
    for (int j = 0; j < 2; ++j) {
        int rr = wid + j * 4;
        float o = pv[0 * 512 + rr * 64 + lane] + pv[1 * 512 + rr * 64 + lane]
                + pv[2 * 512 + rr * 64 + lane] + pv[3 * 512 + rr * 64 + lane];
        out[(bh * N + n0 + rr) * 64 + lane] = o;
    }
}

extern "C" void kernel_launch(void* const* d_in, const int* in_sizes, int n_in,
                              void* d_out, int out_size, void* d_ws, size_t ws_size,
                              hipStream_t stream) {
    const float* q    = (const float*)d_in[0];
    const float* k    = (const float*)d_in[1];
    const float* v    = (const float*)d_in[2];
    const int*   mask = (const int*)d_in[3];
    const float* W_h  = (const float*)d_in[4];
    const float* b_h  = (const float*)d_in[5];
    const float* W_o  = (const float*)d_in[6];
    const float* b_o  = (const float*)d_in[7];
    float* out = (float*)d_out;

    float* qp       = (float*)d_ws;
    _Float16* kpbh  = (_Float16*)(qp + NROWS * 64);
    float* cq6      = (float*)(qp + NROWS * 64 + NROWS * 64);
    float* ck6      = cq6 + NROWS;
    float* w4       = ck6 + NROWS;

    proj_kernel<<<NROWS / 16, 256, 0, stream>>>(q, k, W_h, b_h, W_o, b_o, qp, kpbh, cq6, ck6, w4);
    attn_kernel<<<B * H * (N / QBLK), 256, 0, stream>>>(qp, kpbh, v, mask, cq6, ck6, w4, out);
}

// Round 17
// 38.256 us; speedup vs baseline: 1.1390x; 1.1024x over previous
//
#include <hip/hip_runtime.h>

typedef float v2f __attribute__((ext_vector_type(2)));
typedef _Float16 h8 __attribute__((ext_vector_type(8)));

constexpr int B = 4, H = 8, N = 256, D = 64;
constexpr int QBLK = 8;
constexpr int PATTN_OFF = B * H * N * D;   // 524288
constexpr int NROWS = B * H * N;           // 8192

// ws layout: qp[NROWS*64] f32 | kpbh[NROWS*64] f16 | cq6[NROWS] | ck6[NROWS] | w4[64]

// proj: unchanged from R14 (grid 512, 4 rows/wave, 2 blocks/CU, LDS-transposed
// W_h stride 65 conflict-free; kpb stored f16).
__global__ __launch_bounds__(256, 2) void proj_kernel(
    const float* __restrict__ q, const float* __restrict__ k,
    const float* __restrict__ W_h, const float* __restrict__ b_h,
    const float* __restrict__ W_o, const float* __restrict__ b_o,
    float* __restrict__ qp, _Float16* __restrict__ kpbh,
    float* __restrict__ cq6, float* __restrict__ ck6, float* __restrict__ w4)
{
    __shared__ float WT[128 * 65];
    int t = threadIdx.x;
    int lane = t & 63;
    int wid = __builtin_amdgcn_readfirstlane(t >> 6);
    int bid = blockIdx.x;
    int work = (bid & 7) * 64 + (bid >> 3);   // 512 = 8*64 bijective XCD swizzle

    #pragma unroll
    for (int i = 0; i < 8; ++i) {
        int fidx = (t + i * 256) * 4;
        float4 w = *reinterpret_cast<const float4*>(W_h + fidx);
        int e = fidx >> 7, d = fidx & 127;
        WT[(d + 0) * 65 + e] = w.x;
        WT[(d + 1) * 65 + e] = w.y;
        WT[(d + 2) * 65 + e] = w.z;
        WT[(d + 3) * 65 + e] = w.w;
    }
    if (bid == 0 && t < 64) w4[t] = 0.4f * W_o[t];
    __syncthreads();

    int rbase = work * 16 + wid * 4;   // 4 rows per wave, e = lane
    float accq[4] = {}, acck[4] = {};
    #pragma unroll
    for (int d0 = 0; d0 < 64; d0 += 16) {
        float wq[16], wk[16];
        #pragma unroll
        for (int d = 0; d < 16; ++d) {
            wq[d] = WT[(d0 + d) * 65 + lane];
            wk[d] = WT[(64 + d0 + d) * 65 + lane];
        }
        #pragma unroll
        for (int j = 0; j < 4; ++j) {
            const float* qrow = q + (rbase + j) * 64 + d0;   // wave-uniform -> s_load
            const float* krow = k + (rbase + j) * 64 + d0;
            #pragma unroll
            for (int d = 0; d < 16; ++d) {
                accq[j] = fmaf(qrow[d], wq[d], accq[j]);
                acck[j] = fmaf(krow[d], wk[d], acck[j]);
            }
        }
    }
    float bh_e = b_h[lane];
    float wo = W_o[lane];
    float bo = b_o[0];
    #pragma unroll
    for (int j = 0; j < 4; ++j) {
        float aq = accq[j];
        float ak = acck[j] + bh_e;
        qp[(rbase + j) * 64 + lane] = aq;
        kpbh[(rbase + j) * 64 + lane] = (_Float16)ak;
        float sq = wo * aq, sk = wo * ak;
        #pragma unroll
        for (int off = 32; off > 0; off >>= 1) {
            sq += __shfl_xor(sq, off, 64);
            sk += __shfl_xor(sk, off, 64);
        }
        if (lane == 0) {
            cq6[rbase + j] = 0.6f * sq + bo;
            ck6[rbase + j] = 0.6f * sk;
        }
    }
}

// attn: R14 structure (QBLK=8, grid 1024, 512 thr, e-split halves, packed-fp32
// scores, f16 kv, no-max softmax, f16 p broadcasts in D) with merged phase BC:
// wave wid owns full row wid -> in-wave shfl row-sum; no red_s; 3 barriers.
__global__ __launch_bounds__(512, 2) void attn_kernel(
    const float* __restrict__ qp, const _Float16* __restrict__ kpbh,
    const float* __restrict__ V, const int* __restrict__ mask,
    const float* __restrict__ cq6, const float* __restrict__ ck6,
    const float* __restrict__ w4g,
    float* __restrict__ out)
{
    __shared__ float sc[4096];        // scores [half][row][m]; later PV partials
    __shared__ _Float16 pf[2048];     // [row][m] p as f16 (4 KB)

    int t = threadIdx.x;
    int lane = t & 63;
    int wid = __builtin_amdgcn_readfirstlane(t >> 6);   // 0..7
    int h = wid >> 2;                // 0/1, wave-uniform
    int m = t & 255;
    int bid = blockIdx.x;
    int work = (bid & 7) * 128 + (bid >> 3);   // 1024 = 8*128 bijective
    int bh = work >> 5;
    int nb = work & 31;
    int b = bh >> 3;
    int n0 = nb * QBLK;
    int kvbase = bh * N * 64;

    // kv: kpbh[m][32h .. 32h+31] as 4 x h8 (64 B contiguous, coalesced)
    const h8* kph = reinterpret_cast<const h8*>(kpbh + kvbase + m * 64 + h * 32);
    h8 kh0 = kph[0], kh1 = kph[1], kh2 = kph[2], kh3 = kph[3];

    // mask for merged-BC: wave wid owns row wid; columns c*64+lane (coalesced)
    float mf[4];
    #pragma unroll
    for (int c = 0; c < 4; ++c)
        mf[c] = (mask[(b * N + n0 + wid) * N + c * 64 + lane] != 0) ? 1.0f : 0.0f;

    float ckt = (h == 0) ? ck6[bh * N + m] : 0.f;

    // ---- phase A: packed partial scores for 8 rows over this half's 32 e's ----
    v2f sp2[8];
    const float* cq = cq6 + bh * N + n0;   // uniform
    #pragma unroll
    for (int r = 0; r < 8; ++r) {
        float init = (h == 0) ? (cq[r] + ckt) : 0.f;
        sp2[r] = (v2f){init, 0.f};
    }

    const v2f* qr2 = reinterpret_cast<const v2f*>(qp + (bh * N + n0) * 64 + h * 32);  // uniform
    const v2f* w42 = reinterpret_cast<const v2f*>(w4g + h * 32);                      // uniform
    #pragma unroll
    for (int chunk = 0; chunk < 4; ++chunk) {
        h8 kc = (chunk == 0) ? kh0 : (chunk == 1) ? kh1 : (chunk == 2) ? kh2 : kh3;
        #pragma unroll
        for (int p = 0; p < 4; ++p) {
            v2f w2 = w42[chunk * 4 + p];
            v2f k2 = (v2f){(float)kc[2 * p], (float)kc[2 * p + 1]};
            #pragma unroll
            for (int r = 0; r < 8; ++r) {
                v2f x = qr2[r * 32 + chunk * 4 + p] + k2;           // v_pk_add_f32
                v2f ax = __builtin_elementwise_max(x, -x);          // v_pk_max_f32
                sp2[r] = __builtin_elementwise_fma(w2, ax, sp2[r]); // v_pk_fma_f32
            }
        }
    }
    #pragma unroll
    for (int r = 0; r < 8; ++r)
        sc[h * 2048 + r * 256 + m] = sp2[r].x + sp2[r].y;   // conflict-free

    // V prefetch for phase D group 0 (8 values)
    const float* Vp = V + kvbase + wid * 32 * 64 + lane;
    float vpre[8];
    #pragma unroll
    for (int g = 0; g < 8; ++g) vpre[g] = Vp[g * 64];
    __syncthreads();   // --- barrier 1 ---

    // ---- phase BC (merged): wave wid owns row wid; full in-wave softmax ----
    {
        int r = wid;
        float pv4[4];
        float l = 0.f;
        #pragma unroll
        for (int c = 0; c < 4; ++c) {
            int mm = c * 64 + lane;
            float s = sc[r * 256 + mm] + sc[2048 + r * 256 + mm];
            float p = __expf(s) * mf[c];
            pv4[c] = p;
            l += p;
        }
        #pragma unroll
        for (int off = 32; off > 0; off >>= 1) l += __shfl_xor(l, off, 64);
        float gi = __frcp_rn(l);
        #pragma unroll
        for (int c = 0; c < 4; ++c) {
            int mm = c * 64 + lane;
            float pn = pv4[c] * gi;
            pf[r * 256 + mm] = (_Float16)pn;                      // ds_write_b16
            out[PATTN_OFF + (bh * N + n0 + r) * N + mm] = pn;     // coalesced fp32
        }
    }
    __syncthreads();   // --- barrier 2 (pf ready; sc scores dead) ---

    // ---- phase D: PV. wid = m-chunk of 32, lane = d; f16 p broadcasts ----
    float acc[8] = {};
    {   // group 0 from prefetch
        #pragma unroll
        for (int r = 0; r < 8; ++r) {
            h8 ph = *reinterpret_cast<const h8*>(&pf[r * 256 + wid * 32]);
            #pragma unroll
            for (int g = 0; g < 8; ++g)
                acc[r] = fmaf((float)ph[g], vpre[g], acc[r]);   // -> v_fma_mix_f32
        }
    }
    #pragma unroll
    for (int j = 8; j < 32; j += 8) {
        float vv[8];
        #pragma unroll
        for (int g = 0; g < 8; ++g) vv[g] = Vp[(j + g) * 64];
        #pragma unroll
        for (int r = 0; r < 8; ++r) {
            h8 ph = *reinterpret_cast<const h8*>(&pf[r * 256 + wid * 32 + j]);
            #pragma unroll
            for (int g = 0; g < 8; ++g)
                acc[r] = fmaf((float)ph[g], vv[g], acc[r]);
        }
    }
    // sc scores dead since barrier 2; write PV partials (pf untouched)
    #pragma unroll
    for (int r = 0; r < 8; ++r)
        sc[wid * 512 + r * 64 + lane] = acc[r];
    __syncthreads();   // --- barrier 3 ---

    // final: wave wid owns row wid, lane = d; sum the 8 m-chunk partials
    float o = 0.f;
    #pragma unroll
    for (int mc = 0; mc < 8; ++mc)
        o += sc[mc * 512 + wid * 64 + lane];
    out[(bh * N + n0 + wid) * 64 + lane] = o;
}

extern "C" void kernel_launch(void* const* d_in, const int* in_sizes, int n_in,
                              void* d_out, int out_size, void* d_ws, size_t ws_size,
                              hipStream_t stream) {
    const float* q    = (const float*)d_in[0];
    const float* k    = (const float*)d_in[1];
    const float* v    = (const float*)d_in[2];
    const int*   mask = (const int*)d_in[3];
    const float* W_h  = (const float*)d_in[4];
    const float* b_h  = (const float*)d_in[5];
    const float* W_o  = (const float*)d_in[6];
    const float* b_o  = (const float*)d_in[7];
    float* out = (float*)d_out;

    float* qp       = (float*)d_ws;
    _Float16* kpbh  = (_Float16*)(qp + NROWS * 64);
    float* cq6      = (float*)(qp + NROWS * 64 + NROWS * 64);
    float* ck6      = cq6 + NROWS;
    float* w4       = ck6 + NROWS;

    proj_kernel<<<NROWS / 16, 256, 0, stream>>>(q, k, W_h, b_h, W_o, b_o, qp, kpbh, cq6, ck6, w4);
    attn_kernel<<<B * H * (N / QBLK), 512, 0, stream>>>(qp, kpbh, v, mask, cq6, ck6, w4, out);
}

// Round 18
// 35.124 us; speedup vs baseline: 1.2405x; 1.0892x over previous
//
#include <hip/hip_runtime.h>

typedef float v2f __attribute__((ext_vector_type(2)));
typedef _Float16 h8 __attribute__((ext_vector_type(8)));

constexpr int B = 4, H = 8, N = 256, D = 64;
constexpr int QBLK = 8;
constexpr int PATTN_OFF = B * H * N * D;   // 524288
constexpr int NROWS = B * H * N;           // 8192

// ws layout: qp[NROWS*64] f32 | kpbh[NROWS*64] f16 | cq6[NROWS] | ck6[NROWS] | w4[64]

// proj: R12/R14 structure (grid 512, 4 rows/wave, 2 blocks/CU, LDS-transposed
// W_h stride 65 conflict-free); kpb stored as f16.
__global__ __launch_bounds__(256, 2) void proj_kernel(
    const float* __restrict__ q, const float* __restrict__ k,
    const float* __restrict__ W_h, const float* __restrict__ b_h,
    const float* __restrict__ W_o, const float* __restrict__ b_o,
    float* __restrict__ qp, _Float16* __restrict__ kpbh,
    float* __restrict__ cq6, float* __restrict__ ck6, float* __restrict__ w4)
{
    __shared__ float WT[128 * 65];
    int t = threadIdx.x;
    int lane = t & 63;
    int wid = __builtin_amdgcn_readfirstlane(t >> 6);
    int bid = blockIdx.x;
    int work = (bid & 7) * 64 + (bid >> 3);   // 512 = 8*64 bijective XCD swizzle

    #pragma unroll
    for (int i = 0; i < 8; ++i) {
        int fidx = (t + i * 256) * 4;
        float4 w = *reinterpret_cast<const float4*>(W_h + fidx);
        int e = fidx >> 7, d = fidx & 127;
        WT[(d + 0) * 65 + e] = w.x;
        WT[(d + 1) * 65 + e] = w.y;
        WT[(d + 2) * 65 + e] = w.z;
        WT[(d + 3) * 65 + e] = w.w;
    }
    if (bid == 0 && t < 64) w4[t] = 0.4f * W_o[t];
    __syncthreads();

    int rbase = work * 16 + wid * 4;   // 4 rows per wave, e = lane
    float accq[4] = {}, acck[4] = {};
    #pragma unroll
    for (int d0 = 0; d0 < 64; d0 += 16) {
        float wq[16], wk[16];
        #pragma unroll
        for (int d = 0; d < 16; ++d) {
            wq[d] = WT[(d0 + d) * 65 + lane];
            wk[d] = WT[(64 + d0 + d) * 65 + lane];
        }
        #pragma unroll
        for (int j = 0; j < 4; ++j) {
            const float* qrow = q + (rbase + j) * 64 + d0;   // wave-uniform -> s_load
            const float* krow = k + (rbase + j) * 64 + d0;
            #pragma unroll
            for (int d = 0; d < 16; ++d) {
                accq[j] = fmaf(qrow[d], wq[d], accq[j]);
                acck[j] = fmaf(krow[d], wk[d], acck[j]);
            }
        }
    }
    float bh_e = b_h[lane];
    float wo = W_o[lane];
    float bo = b_o[0];
    #pragma unroll
    for (int j = 0; j < 4; ++j) {
        float aq = accq[j];
        float ak = acck[j] + bh_e;
        qp[(rbase + j) * 64 + lane] = aq;
        kpbh[(rbase + j) * 64 + lane] = (_Float16)ak;
        float sq = wo * aq, sk = wo * ak;
        #pragma unroll
        for (int off = 32; off > 0; off >>= 1) {
            sq += __shfl_xor(sq, off, 64);
            sk += __shfl_xor(sk, off, 64);
        }
        if (lane == 0) {
            cq6[rbase + j] = 0.6f * sq + bo;
            ck6[rbase + j] = 0.6f * sk;
        }
    }
}

// attn: R14 exactly — QBLK=8, grid 1024, 512 thr, e-split halves, packed-fp32
// scores, f16 kv, no-max softmax, f16 p broadcasts in D, 4 barriers.
__global__ __launch_bounds__(512, 2) void attn_kernel(
    const float* __restrict__ qp, const _Float16* __restrict__ kpbh,
    const float* __restrict__ V, const int* __restrict__ mask,
    const float* __restrict__ cq6, const float* __restrict__ ck6,
    const float* __restrict__ w4g,
    float* __restrict__ out)
{
    __shared__ float sc[4096];        // scores [half][row][m]; later PV partials
    __shared__ _Float16 pf[2048];     // [row][m] p as f16 (4 KB)
    __shared__ float red_s[8][4];

    int t = threadIdx.x;
    int lane = t & 63;
    int wid = __builtin_amdgcn_readfirstlane(t >> 6);   // 0..7
    int h = wid >> 2;                // 0/1, wave-uniform
    int m = t & 255;
    int bid = blockIdx.x;
    int work = (bid & 7) * 128 + (bid >> 3);   // 1024 = 8*128 bijective
    int bh = work >> 5;
    int nb = work & 31;
    int b = bh >> 3;
    int n0 = nb * QBLK;
    int kvbase = bh * N * 64;

    // kv: kpbh[m][32h .. 32h+31] as 4 x h8 (64 B contiguous, coalesced)
    const h8* kph = reinterpret_cast<const h8*>(kpbh + kvbase + m * 64 + h * 32);
    h8 kh0 = kph[0], kh1 = kph[1], kh2 = kph[2], kh3 = kph[3];

    float mf[4];
    #pragma unroll
    for (int i = 0; i < 4; ++i)
        mf[i] = (mask[(b * N + n0 + h * 4 + i) * N + m] != 0) ? 1.0f : 0.0f;

    float ckt = (h == 0) ? ck6[bh * N + m] : 0.f;

    // ---- phase A: packed partial scores for 8 rows over this half's 32 e's ----
    v2f sp2[8];
    const float* cq = cq6 + bh * N + n0;   // uniform
    #pragma unroll
    for (int r = 0; r < 8; ++r) {
        float init = (h == 0) ? (cq[r] + ckt) : 0.f;
        sp2[r] = (v2f){init, 0.f};
    }

    const v2f* qr2 = reinterpret_cast<const v2f*>(qp + (bh * N + n0) * 64 + h * 32);  // uniform
    const v2f* w42 = reinterpret_cast<const v2f*>(w4g + h * 32);                      // uniform
    #pragma unroll
    for (int chunk = 0; chunk < 4; ++chunk) {
        h8 kc = (chunk == 0) ? kh0 : (chunk == 1) ? kh1 : (chunk == 2) ? kh2 : kh3;
        #pragma unroll
        for (int p = 0; p < 4; ++p) {
            v2f w2 = w42[chunk * 4 + p];
            v2f k2 = (v2f){(float)kc[2 * p], (float)kc[2 * p + 1]};
            #pragma unroll
            for (int r = 0; r < 8; ++r) {
                v2f x = qr2[r * 32 + chunk * 4 + p] + k2;           // v_pk_add_f32
                v2f ax = __builtin_elementwise_max(x, -x);          // v_pk_max_f32
                sp2[r] = __builtin_elementwise_fma(w2, ax, sp2[r]); // v_pk_fma_f32
            }
        }
    }
    #pragma unroll
    for (int r = 0; r < 8; ++r)
        sc[h * 2048 + r * 256 + m] = sp2[r].x + sp2[r].y;   // conflict-free

    // V prefetch for phase D group 0 (8 values)
    const float* Vp = V + kvbase + wid * 32 * 64 + lane;
    float vpre[8];
    #pragma unroll
    for (int g = 0; g < 8; ++g) vpre[g] = Vp[g * 64];
    __syncthreads();

    // ---- phase B: rows h*4..h*4+3, this wave's 64-m chunk; no max pass ----
    float p8[4];
    #pragma unroll
    for (int i = 0; i < 4; ++i) {
        int rr = h * 4 + i;
        float s = sc[rr * 256 + m] + sc[2048 + rr * 256 + m];
        float p = __expf(s) * mf[i];
        p8[i] = p;
        float l = p;
        #pragma unroll
        for (int off = 32; off > 0; off >>= 1) l += __shfl_xor(l, off, 64);
        if (lane == 0) red_s[wid][i] = l;
    }
    __syncthreads();

    // ---- phase C: merge sums; write p_attn (fp32 global) + pf (f16 LDS) ----
    #pragma unroll
    for (int i = 0; i < 4; ++i) {
        int rr = h * 4 + i;
        float gs = red_s[h*4+0][i] + red_s[h*4+1][i] + red_s[h*4+2][i] + red_s[h*4+3][i];
        float pn = p8[i] * __frcp_rn(gs);
        pf[rr * 256 + m] = (_Float16)pn;                      // ds_write_b16
        out[PATTN_OFF + (bh * N + n0 + rr) * N + m] = pn;     // coalesced fp32
    }
    __syncthreads();

    // ---- phase D: PV. wid = m-chunk of 32, lane = d; f16 p broadcasts ----
    float acc[8] = {};
    {   // group 0 from prefetch
        #pragma unroll
        for (int r = 0; r < 8; ++r) {
            h8 ph = *reinterpret_cast<const h8*>(&pf[r * 256 + wid * 32]);
            #pragma unroll
            for (int g = 0; g < 8; ++g)
                acc[r] = fmaf((float)ph[g], vpre[g], acc[r]);   // -> v_fma_mix_f32
        }
    }
    #pragma unroll
    for (int j = 8; j < 32; j += 8) {
        float vv[8];
        #pragma unroll
        for (int g = 0; g < 8; ++g) vv[g] = Vp[(j + g) * 64];
        #pragma unroll
        for (int r = 0; r < 8; ++r) {
            h8 ph = *reinterpret_cast<const h8*>(&pf[r * 256 + wid * 32 + j]);
            #pragma unroll
            for (int g = 0; g < 8; ++g)
                acc[r] = fmaf((float)ph[g], vv[g], acc[r]);
        }
    }
    __syncthreads();   // sc score region dead; reuse for PV partials

    #pragma unroll
    for (int r = 0; r < 8; ++r)
        sc[wid * 512 + r * 64 + lane] = acc[r];
    __syncthreads();

    // final: wave wid owns row wid, lane = d; sum the 8 m-chunk partials
    float o = 0.f;
    #pragma unroll
    for (int mc = 0; mc < 8; ++mc)
        o += sc[mc * 512 + wid * 64 + lane];
    out[(bh * N + n0 + wid) * 64 + lane] = o;
}

extern "C" void kernel_launch(void* const* d_in, const int* in_sizes, int n_in,
                              void* d_out, int out_size, void* d_ws, size_t ws_size,
                              hipStream_t stream) {
    const float* q    = (const float*)d_in[0];
    const float* k    = (const float*)d_in[1];
    const float* v    = (const float*)d_in[2];
    const int*   mask = (const int*)d_in[3];
    const float* W_h  = (const float*)d_in[4];
    const float* b_h  = (const float*)d_in[5];
    const float* W_o  = (const float*)d_in[6];
    const float* b_o  = (const float*)d_in[7];
    float* out = (float*)d_out;

    float* qp       = (float*)d_ws;
    _Float16* kpbh  = (_Float16*)(qp + NROWS * 64);
    float* cq6      = (float*)(qp + NROWS * 64 + NROWS * 64);
    float* ck6      = cq6 + NROWS;
    float* w4       = ck6 + NROWS;

    proj_kernel<<<NROWS / 16, 256, 0, stream>>>(q, k, W_h, b_h, W_o, b_o, qp, kpbh, cq6, ck6, w4);
    attn_kernel<<<B * H * (N / QBLK), 512, 0, stream>>>(qp, kpbh, v, mask, cq6, ck6, w4, out);
}